// Round 13
// baseline (98.181 us; speedup 1.0000x reference)
//
#include <hip/hip_runtime.h>
#include <math.h>

#define BB 4
#define SS 4096
#define DK 5
#define TILE 1024          // keys per LDS tile
#define NT 256
// (1/sqrt(5)) * log2(e) folded into a' so p = v_exp_f32(score)
#define LAM (0.44721359549995793f * 1.4426950408889634f)

typedef float v2f __attribute__((ext_vector_type(2)));

__device__ __forceinline__ float fast_exp2(float x) {
#if __has_builtin(__builtin_amdgcn_exp2f)
    return __builtin_amdgcn_exp2f(x);
#else
    float r; asm("v_exp_f32 %0, %1" : "=v"(r) : "v"(x)); return r;
#endif
}

// Packed fp32: compiler selects v_pk_fma_f32 on gfx90a+ for <2 x float> fma.
__device__ __forceinline__ v2f pk_fma(v2f a, v2f b, v2f c) {
    return __builtin_elementwise_fma(a, b, c);
}

// async global->LDS, 16B per lane (dest lane-contiguous within each wave)
#define GLOAD16(gp, lp)                                                        \
    __builtin_amdgcn_global_load_lds(                                          \
        (const __attribute__((address_space(1))) unsigned int*)(gp),           \
        (__attribute__((address_space(3))) unsigned int*)(lp), 16, 0, 0)

// ---------------------------------------------------------------------------
// Single kernel. V folded out (out = (Wv·Σp x + bv Σp)/l), biases folded
// into a' -> per-key data is x_k itself, staged AoS straight from x into a
// 2-deep LDS pipeline (stage tile t+1 overlapped with compute of tile t,
// ONE barrier per tile). Each wave owns 8 rows: 4 low + 4 high mirror
// (uniform work per wave and per block). 512 blocks = 2 blocks/CU exactly.
//   score_rk = a'_r·x_k,  a'_r = LAM*(M^T x_r + Wk^T bq),  M = Wq^T Wk
//   acc_r = {Σ_past p·x, Σ_past p},  l_r = Σ_all p
//   out_r,d = (Wv[d]·acc_x + bv[d]·acc_p)/l_r
// AoS ds_read: 3 x b128 per lane at stride 48B -> uniform 8 dwords/bank,
// conflict-free. Spill-safe per-row fused score->exp->l->acc (R8 lesson).
// ---------------------------------------------------------------------------
__global__ __launch_bounds__(NT, 2) void attn(
    const float* __restrict__ x,
    const float* __restrict__ Wq, const float* __restrict__ bq,
    const float* __restrict__ Wk,
    const float* __restrict__ Wv, const float* __restrict__ bv,
    float* __restrict__ out)
{
    __shared__ float kls[2][TILE * 3];     // AoS: key k at [k*3 .. k*3+2]

    const int tid = threadIdx.x;
    const int sub = tid & 63;
    const int wave = tid >> 6;

    const int b = blockIdx.x >> 7;         // 128 blocks per batch
    const int j = blockIdx.x & 127;
    const int lo0 = j * 16 + wave * 4;             // low quad
    const int hi0 = (255 - j) * 16 + wave * 4;     // mirror high quad
    int rows[8];
#pragma unroll
    for (int r = 0; r < 4; ++r) { rows[r] = lo0 + r; rows[4 + r] = hi0 + r; }

    // M = Wq^T Wk (3x3) and u = Wk^T bq (uniform)
    float M00=0,M01=0,M02=0,M10=0,M11=0,M12=0,M20=0,M21=0,M22=0;
    float u0=0,u1=0,u2=0;
#pragma unroll
    for (int d = 0; d < DK; ++d) {
        float q0 = Wq[d*3+0], q1 = Wq[d*3+1], q2 = Wq[d*3+2];
        float k0 = Wk[d*3+0], k1 = Wk[d*3+1], k2 = Wk[d*3+2];
        float bqd = bq[d];
        M00 = fmaf(q0,k0,M00); M01 = fmaf(q0,k1,M01); M02 = fmaf(q0,k2,M02);
        M10 = fmaf(q1,k0,M10); M11 = fmaf(q1,k1,M11); M12 = fmaf(q1,k2,M12);
        M20 = fmaf(q2,k0,M20); M21 = fmaf(q2,k1,M21); M22 = fmaf(q2,k2,M22);
        u0 = fmaf(k0,bqd,u0);  u1 = fmaf(k1,bqd,u1);  u2 = fmaf(k2,bqd,u2);
    }

    const float* xb = x + (size_t)b * SS * 3;

    // per-row a' (broadcast into both packed halves)
    v2f a2[8][3];
#pragma unroll
    for (int r = 0; r < 8; ++r) {
        const float* xr = &xb[(size_t)rows[r] * 3];
        float x0 = xr[0], x1 = xr[1], x2 = xr[2];
        float av0 = LAM * (x0*M00 + x1*M10 + x2*M20 + u0);
        float av1 = LAM * (x0*M01 + x1*M11 + x2*M21 + u1);
        float av2 = LAM * (x0*M02 + x1*M12 + x2*M22 + u2);
        a2[r][0] = (v2f){av0, av0};
        a2[r][1] = (v2f){av1, av1};
        a2[r][2] = (v2f){av2, av2};
    }

    // per-lane epilogue weights (lane sub<5 owns output dim sub)
    float wv0 = 0.f, wv1 = 0.f, wv2 = 0.f, bvl = 0.f;
    if (sub < DK) {
        wv0 = Wv[sub*3+0]; wv1 = Wv[sub*3+1]; wv2 = Wv[sub*3+2]; bvl = bv[sub];
    }

    v2f l2[8];
    v2f acc2[8][4];              // {p*x0, p*x1, p*x2, p} over past keys
#pragma unroll
    for (int r = 0; r < 8; ++r) {
        l2[r] = (v2f){0.f, 0.f};
#pragma unroll
        for (int d = 0; d < 4; ++d) acc2[r][d] = (v2f){0.f, 0.f};
    }

    // ---- prologue: stage tile 0 into buffer 0 (3 x 16B per thread) ----
#pragma unroll
    for (int it = 0; it < 3; ++it) {
        int idx = it * NT + tid;               // 0..767 float4 slots
        GLOAD16(xb + idx * 4, &kls[0][idx * 4]);
    }

#pragma unroll 2
    for (int t = 0; t < SS / TILE; ++t) {      // 4 tiles
        const int buf = t & 1;
        __syncthreads();                       // drains stage of buf; all waves
                                               // done computing on buf^1
        if (t < SS / TILE - 1) {               // stage next tile into buf^1
#pragma unroll
            for (int it = 0; it < 3; ++it) {
                int idx = it * NT + tid;
                GLOAD16(xb + (size_t)(t + 1) * TILE * 3 + idx * 4,
                        &kls[buf ^ 1][idx * 4]);
            }
        }

#pragma unroll
        for (int c = 0; c < TILE / 256; ++c) { // 4 chunks of 256 keys
            const int cstart = t * TILE + c * 256;
            const int cend   = cstart + 255;
            const int kbase  = cstart + sub * 4;
            const int off    = (c * 256 + sub * 4) * 3;

            float4 f0 = *(const float4*)&kls[buf][off + 0];
            float4 f1 = *(const float4*)&kls[buf][off + 4];
            float4 f2 = *(const float4*)&kls[buf][off + 8];

            // AoS -> packed key-pair slices
#pragma unroll
            for (int h = 0; h < 2; ++h) {
                const int kgh = kbase + h * 2;
                v2f k0, k1, k2;
                if (h == 0) {
                    k0 = (v2f){f0.x, f0.w};
                    k1 = (v2f){f0.y, f1.x};
                    k2 = (v2f){f0.z, f1.y};
                } else {
                    k0 = (v2f){f1.z, f2.y};
                    k1 = (v2f){f1.w, f2.z};
                    k2 = (v2f){f2.x, f2.w};
                }
#pragma unroll
                for (int r = 0; r < 8; ++r) {
                    const int row = rows[r];
                    v2f sc = pk_fma(a2[r][0], k0,
                             pk_fma(a2[r][1], k1, a2[r][2] * k2));
                    v2f p;
                    p.x = fast_exp2(sc.x); p.y = fast_exp2(sc.y);
                    l2[r] += p;
                    if (cend <= row) {              // full accumulate
                        acc2[r][0] = pk_fma(p, k0, acc2[r][0]);
                        acc2[r][1] = pk_fma(p, k1, acc2[r][1]);
                        acc2[r][2] = pk_fma(p, k2, acc2[r][2]);
                        acc2[r][3] += p;
                    } else if (cstart <= row) {     // boundary: masked
                        v2f pm;
                        pm.x = (kgh + 0 <= row) ? p.x : 0.f;
                        pm.y = (kgh + 1 <= row) ? p.y : 0.f;
                        acc2[r][0] = pk_fma(pm, k0, acc2[r][0]);
                        acc2[r][1] = pk_fma(pm, k1, acc2[r][1]);
                        acc2[r][2] = pk_fma(pm, k2, acc2[r][2]);
                        acc2[r][3] += pm;
                    }
                    // else: future-only for this row -> denominator only
                }
            }
        }
    }

    // fold packed halves, butterfly-reduce 5 values across 64 lanes, project
#pragma unroll
    for (int r = 0; r < 8; ++r) {
        float lr = l2[r].x + l2[r].y;
        float A0 = acc2[r][0].x + acc2[r][0].y;
        float A1 = acc2[r][1].x + acc2[r][1].y;
        float A2 = acc2[r][2].x + acc2[r][2].y;
        float PS = acc2[r][3].x + acc2[r][3].y;
#pragma unroll
        for (int off = 32; off >= 1; off >>= 1) {
            lr += __shfl_xor(lr, off);
            A0 += __shfl_xor(A0, off);
            A1 += __shfl_xor(A1, off);
            A2 += __shfl_xor(A2, off);
            PS += __shfl_xor(PS, off);
        }
        if (sub < DK) {
            float num = fmaf(wv0, A0, fmaf(wv1, A1, fmaf(wv2, A2, bvl * PS)));
            out[((size_t)b * SS + rows[r]) * DK + sub] = num / lr;
        }
    }
}

extern "C" void kernel_launch(void* const* d_in, const int* in_sizes, int n_in,
                              void* d_out, int out_size, void* d_ws, size_t ws_size,
                              hipStream_t stream) {
    const float* x  = (const float*)d_in[0];
    const float* Wq = (const float*)d_in[1];
    const float* bq = (const float*)d_in[2];
    const float* Wk = (const float*)d_in[3];
    const float* Wv = (const float*)d_in[5];
    const float* bv = (const float*)d_in[6];
    float* outp = (float*)d_out;

    attn<<<BB * 128, NT, 0, stream>>>(x, Wq, bq, Wk, Wv, bv, outp);
}

// Round 14
// 66.675 us; speedup vs baseline: 1.4725x; 1.4725x over previous
//
#include <hip/hip_runtime.h>
#include <math.h>

#define BB 4
#define SS 4096
#define DK 5
#define TILE 1024
#define NT 256
// (1/sqrt(5)) * log2(e) folded into a' so p = v_exp_f32(score)
#define LAM (0.44721359549995793f * 1.4426950408889634f)

typedef float v2f __attribute__((ext_vector_type(2)));

__device__ __forceinline__ float fast_exp2(float x) {
#if __has_builtin(__builtin_amdgcn_exp2f)
    return __builtin_amdgcn_exp2f(x);
#else
    float r; asm("v_exp_f32 %0, %1" : "=v"(r) : "v"(x)); return r;
#endif
}

// Packed fp32: compiler selects v_pk_fma_f32 on gfx90a+ for <2 x float> fma.
__device__ __forceinline__ v2f pk_fma(v2f a, v2f b, v2f c) {
    return __builtin_elementwise_fma(a, b, c);
}

// async global->LDS, 16B per lane (dest lane-contiguous)
#define GLOAD16(gp, lp)                                                        \
    __builtin_amdgcn_global_load_lds(                                          \
        (const __attribute__((address_space(1))) unsigned int*)(gp),           \
        (__attribute__((address_space(3))) unsigned int*)(lp), 16, 0, 0)

// ---------------------------------------------------------------------------
// Kernel 1: transpose x -> Xt[B][3][S] (SoA so staging + b128 LDS reads are
// contiguous). All other preprocessing is folded: V through the attention
// sum, biases into a'.
// ---------------------------------------------------------------------------
__global__ __launch_bounds__(NT) void proj_x(
    const float* __restrict__ x, float* __restrict__ Xt)
{
    int gid = blockIdx.x * NT + threadIdx.x;
    if (gid >= BB * SS) return;
    int b = gid >> 12;
    int s = gid & (SS - 1);
    float* XtB = Xt + (size_t)b * 3 * SS;
    XtB[0 * SS + s] = x[gid * 3 + 0];
    XtB[1 * SS + s] = x[gid * 3 + 1];
    XtB[2 * SS + s] = x[gid * 3 + 2];
}

// ---------------------------------------------------------------------------
// Kernel 2: attention, V folded out.
//   score_rk = a'_r·x_k,  a'_r = LAM*(M^T x_r + Wk^T bq),  M = Wq^T Wk
//   acc_r = {Σ_past p·x, Σ_past p},  l_r = Σ_all p
//   out_r,d = (Wv[d]·acc_x + bv[d]·acc_p)/l_r
// BALANCED waves: every wave owns 2 low + 2 high mirror rows (4 total — the
// proven register budget; 8 spilled in R13). With V folded there is no
// V-traffic penalty for balance: the accumulate operand IS the k registers.
// 2-deep LDS pipeline: stage tile t+1 (async global->LDS) overlapped with
// compute of tile t, ONE barrier per tile. 24 KB LDS -> 4 blocks/CU.
// ---------------------------------------------------------------------------
__global__ __launch_bounds__(NT, 4) void attn(
    const float* __restrict__ x,
    const float* __restrict__ Wq, const float* __restrict__ bq,
    const float* __restrict__ Wk,
    const float* __restrict__ Wv, const float* __restrict__ bv,
    const float* __restrict__ Xt,
    float* __restrict__ out)
{
    __shared__ float kls[2][3][TILE];

    const int tid = threadIdx.x;
    const int sub = tid & 63;
    const int wave = tid >> 6;

    const int b = blockIdx.x >> 8;
    const int i = blockIdx.x & 255;
    const int lo0 = i * 8 + wave * 2;          // rows: lo0, lo0+1, hi0, hi0+1
    const int hi0 = (511 - i) * 8 + wave * 2;
    const int rows[4] = {lo0, lo0 + 1, hi0, hi0 + 1};

    // M = Wq^T Wk (3x3) and u = Wk^T bq (uniform)
    float M00=0,M01=0,M02=0,M10=0,M11=0,M12=0,M20=0,M21=0,M22=0;
    float u0=0,u1=0,u2=0;
#pragma unroll
    for (int d = 0; d < DK; ++d) {
        float q0 = Wq[d*3+0], q1 = Wq[d*3+1], q2 = Wq[d*3+2];
        float k0 = Wk[d*3+0], k1 = Wk[d*3+1], k2 = Wk[d*3+2];
        float bqd = bq[d];
        M00 = fmaf(q0,k0,M00); M01 = fmaf(q0,k1,M01); M02 = fmaf(q0,k2,M02);
        M10 = fmaf(q1,k0,M10); M11 = fmaf(q1,k1,M11); M12 = fmaf(q1,k2,M12);
        M20 = fmaf(q2,k0,M20); M21 = fmaf(q2,k1,M21); M22 = fmaf(q2,k2,M22);
        u0 = fmaf(k0,bqd,u0);  u1 = fmaf(k1,bqd,u1);  u2 = fmaf(k2,bqd,u2);
    }

    const float* xb = x + (size_t)b * SS * 3;

    // per-row a' (broadcast into both packed halves)
    v2f a2[4][3];
#pragma unroll
    for (int r = 0; r < 4; ++r) {
        const float* xr = &xb[(size_t)rows[r] * 3];
        float x0 = xr[0], x1 = xr[1], x2 = xr[2];
        float av0 = LAM * (x0*M00 + x1*M10 + x2*M20 + u0);
        float av1 = LAM * (x0*M01 + x1*M11 + x2*M21 + u1);
        float av2 = LAM * (x0*M02 + x1*M12 + x2*M22 + u2);
        a2[r][0] = (v2f){av0, av0};
        a2[r][1] = (v2f){av1, av1};
        a2[r][2] = (v2f){av2, av2};
    }

    // per-lane epilogue weights (lane sub<5 owns output dim sub)
    float wv0 = 0.f, wv1 = 0.f, wv2 = 0.f, bvl = 0.f;
    if (sub < DK) {
        wv0 = Wv[sub*3+0]; wv1 = Wv[sub*3+1]; wv2 = Wv[sub*3+2]; bvl = bv[sub];
    }

    v2f l2[4];
    v2f acc2[4][4];              // {p*x0, p*x1, p*x2, p} over past keys
#pragma unroll
    for (int r = 0; r < 4; ++r) {
        l2[r] = (v2f){0.f, 0.f};
#pragma unroll
        for (int d = 0; d < 4; ++d) acc2[r][d] = (v2f){0.f, 0.f};
    }

    const float* XtB = Xt + (size_t)b * 3 * SS;

    // ---- prologue: stage tile 0 into buffer 0 ----
#pragma unroll
    for (int it = 0; it < 3; ++it) {
        int idx = it * NT + tid;               // 0..767 float4 slots
        int d = idx >> 8, c4 = idx & 255;
        GLOAD16(&XtB[(size_t)d * SS + c4 * 4], &kls[0][d][c4 * 4]);
    }

    for (int t = 0; t < SS / TILE; ++t) {      // 4 tiles
        const int buf = t & 1;
        __syncthreads();   // stage of buf complete (vmcnt drained) AND all
                           // waves finished reading buf^1 from prev tile
        if (t < SS / TILE - 1) {               // stage next tile into buf^1
#pragma unroll
            for (int it = 0; it < 3; ++it) {
                int idx = it * NT + tid;
                int d = idx >> 8, c4 = idx & 255;
                GLOAD16(&XtB[(size_t)d * SS + (t + 1) * TILE + c4 * 4],
                        &kls[buf ^ 1][d][c4 * 4]);
            }
        }

#pragma unroll
        for (int c = 0; c < TILE / 256; ++c) { // 4 chunks of 256 keys
            const int key = c * 256 + sub * 4;
            const int cstart = t * TILE + c * 256;
            const int cend   = cstart + 255;
            const int kbase  = cstart + sub * 4;

            float4 kt0 = *(const float4*)&kls[buf][0][key];
            float4 kt1 = *(const float4*)&kls[buf][1][key];
            float4 kt2 = *(const float4*)&kls[buf][2][key];

#pragma unroll
            for (int h = 0; h < 2; ++h) {
                const int kgh = kbase + h * 2;
                v2f k0 = ((v2f*)&kt0)[h];
                v2f k1 = ((v2f*)&kt1)[h];
                v2f k2 = ((v2f*)&kt2)[h];
#pragma unroll
                for (int r = 0; r < 4; ++r) {
                    const int row = rows[r];
                    v2f sc = pk_fma(a2[r][0], k0,
                             pk_fma(a2[r][1], k1, a2[r][2] * k2));
                    v2f p;
                    p.x = fast_exp2(sc.x); p.y = fast_exp2(sc.y);
                    l2[r] += p;
                    if (cend <= row) {              // full accumulate
                        acc2[r][0] = pk_fma(p, k0, acc2[r][0]);
                        acc2[r][1] = pk_fma(p, k1, acc2[r][1]);
                        acc2[r][2] = pk_fma(p, k2, acc2[r][2]);
                        acc2[r][3] += p;
                    } else if (cstart <= row) {     // boundary: masked
                        v2f pm;
                        pm.x = (kgh + 0 <= row) ? p.x : 0.f;
                        pm.y = (kgh + 1 <= row) ? p.y : 0.f;
                        acc2[r][0] = pk_fma(pm, k0, acc2[r][0]);
                        acc2[r][1] = pk_fma(pm, k1, acc2[r][1]);
                        acc2[r][2] = pk_fma(pm, k2, acc2[r][2]);
                        acc2[r][3] += pm;
                    }
                    // else: future-only for this row -> denominator only
                }
            }
        }
    }

    // fold packed halves, butterfly-reduce 5 values across 64 lanes, project
#pragma unroll
    for (int r = 0; r < 4; ++r) {
        float lr = l2[r].x + l2[r].y;
        float A0 = acc2[r][0].x + acc2[r][0].y;
        float A1 = acc2[r][1].x + acc2[r][1].y;
        float A2 = acc2[r][2].x + acc2[r][2].y;
        float PS = acc2[r][3].x + acc2[r][3].y;
#pragma unroll
        for (int off = 32; off >= 1; off >>= 1) {
            lr += __shfl_xor(lr, off);
            A0 += __shfl_xor(A0, off);
            A1 += __shfl_xor(A1, off);
            A2 += __shfl_xor(A2, off);
            PS += __shfl_xor(PS, off);
        }
        if (sub < DK) {
            float num = fmaf(wv0, A0, fmaf(wv1, A1, fmaf(wv2, A2, bvl * PS)));
            out[((size_t)b * SS + rows[r]) * DK + sub] = num / lr;
        }
    }
}

extern "C" void kernel_launch(void* const* d_in, const int* in_sizes, int n_in,
                              void* d_out, int out_size, void* d_ws, size_t ws_size,
                              hipStream_t stream) {
    const float* x  = (const float*)d_in[0];
    const float* Wq = (const float*)d_in[1];
    const float* bq = (const float*)d_in[2];
    const float* Wk = (const float*)d_in[3];
    const float* Wv = (const float*)d_in[5];
    const float* bv = (const float*)d_in[6];
    float* outp = (float*)d_out;

    float* Xt = (float*)d_ws;                       // [B][3][S] f32 (196 KB)

    proj_x<<<(BB * SS + NT - 1) / NT, NT, 0, stream>>>(x, Xt);
    attn<<<BB * (SS / 16), NT, 0, stream>>>(x, Wq, bq, Wk, Wv, bv, Xt, outp);
}

// Round 15
// 36.283 us; speedup vs baseline: 2.7060x; 1.8376x over previous
//
#include <hip/hip_runtime.h>
#include <math.h>

#define BB 4
#define SS 4096
#define DK 5
#define TK 1024
#define NT 256
// (1/sqrt(5)) * log2(e) folded into a' so p = v_exp_f32(score)
#define LAM (0.44721359549995793f * 1.4426950408889634f)

typedef float v2f __attribute__((ext_vector_type(2)));

__device__ __forceinline__ float fast_exp2(float x) {
#if __has_builtin(__builtin_amdgcn_exp2f)
    return __builtin_amdgcn_exp2f(x);
#else
    float r; asm("v_exp_f32 %0, %1" : "=v"(r) : "v"(x)); return r;
#endif
}

// Packed fp32: compiler selects v_pk_fma_f32 on gfx90a+ for <2 x float> fma.
__device__ __forceinline__ v2f pk_fma(v2f a, v2f b, v2f c) {
    return __builtin_elementwise_fma(a, b, c);
}

// async global->LDS, 16B per lane (dest lane-contiguous)
#define GLOAD16(gp, lp)                                                        \
    __builtin_amdgcn_global_load_lds(                                          \
        (const __attribute__((address_space(1))) unsigned int*)(gp),           \
        (__attribute__((address_space(3))) unsigned int*)(lp), 16, 0, 0)

// ---------------------------------------------------------------------------
// Kernel 1: transpose x -> Xt[B][3][S] (SoA for contiguous staging).
// Everything else is folded: V through the attention sum, biases into a'.
// ---------------------------------------------------------------------------
__global__ __launch_bounds__(NT) void proj_x(
    const float* __restrict__ x, float* __restrict__ Xt)
{
    int gid = blockIdx.x * NT + threadIdx.x;
    if (gid >= BB * SS) return;
    int b = gid >> 12;
    int s = gid & (SS - 1);
    float* XtB = Xt + (size_t)b * 3 * SS;
    XtB[0 * SS + s] = x[gid * 3 + 0];
    XtB[1 * SS + s] = x[gid * 3 + 1];
    XtB[2 * SS + s] = x[gid * 3 + 2];
}

// ---------------------------------------------------------------------------
// Kernel 2: attention = R8's proven spill-free skeleton with V folded out.
//   score_rk = a'_r·x_k,  a'_r = LAM*(M^T x_r + Wk^T bq),  M = Wq^T Wk
//   acc_r = {Σ_past p·x, Σ_past p},  l_r = Σ_all p
//   out_r,d = (Wv[d]·acc_x + bv[d]·acc_p)/l_r
// Balanced waves (2 low + 2 high mirror rows each: uniform work per wave ->
// no barrier stranding). Plain __launch_bounds__(NT) (R8: no min -> no
// allocator cliff). TK=1024 serial staging, 3 planes = 12 KB LDS. b64
// half-loads; per-row fused score->exp->l->gated-acc in one wave-uniform
// anyAcc scope (R8's exact shape).
// ---------------------------------------------------------------------------
__global__ __launch_bounds__(NT) void attn(
    const float* __restrict__ x,
    const float* __restrict__ Wq, const float* __restrict__ bq,
    const float* __restrict__ Wk,
    const float* __restrict__ Wv, const float* __restrict__ bv,
    const float* __restrict__ Xt,
    float* __restrict__ out)
{
    __shared__ float kls[3][TK];

    const int tid = threadIdx.x;
    const int sub = tid & 63;
    const int wave = tid >> 6;

    const int b = blockIdx.x >> 8;
    const int i = blockIdx.x & 255;
    const int lo0 = i * 8 + wave * 2;          // rows: lo0, lo0+1, hi0, hi0+1
    const int hi0 = (511 - i) * 8 + wave * 2;
    const int rows[4] = {lo0, lo0 + 1, hi0, hi0 + 1};

    // M = Wq^T Wk (3x3) and u = Wk^T bq (uniform)
    float M00=0,M01=0,M02=0,M10=0,M11=0,M12=0,M20=0,M21=0,M22=0;
    float u0=0,u1=0,u2=0;
#pragma unroll
    for (int d = 0; d < DK; ++d) {
        float q0 = Wq[d*3+0], q1 = Wq[d*3+1], q2 = Wq[d*3+2];
        float k0 = Wk[d*3+0], k1 = Wk[d*3+1], k2 = Wk[d*3+2];
        float bqd = bq[d];
        M00 = fmaf(q0,k0,M00); M01 = fmaf(q0,k1,M01); M02 = fmaf(q0,k2,M02);
        M10 = fmaf(q1,k0,M10); M11 = fmaf(q1,k1,M11); M12 = fmaf(q1,k2,M12);
        M20 = fmaf(q2,k0,M20); M21 = fmaf(q2,k1,M21); M22 = fmaf(q2,k2,M22);
        u0 = fmaf(k0,bqd,u0);  u1 = fmaf(k1,bqd,u1);  u2 = fmaf(k2,bqd,u2);
    }

    const float* xb = x + (size_t)b * SS * 3;

    // per-row a' (broadcast into both packed halves)
    v2f a2[4][3];
#pragma unroll
    for (int r = 0; r < 4; ++r) {
        const float* xr = &xb[(size_t)rows[r] * 3];
        float x0 = xr[0], x1 = xr[1], x2 = xr[2];
        float av0 = LAM * (x0*M00 + x1*M10 + x2*M20 + u0);
        float av1 = LAM * (x0*M01 + x1*M11 + x2*M21 + u1);
        float av2 = LAM * (x0*M02 + x1*M12 + x2*M22 + u2);
        a2[r][0] = (v2f){av0, av0};
        a2[r][1] = (v2f){av1, av1};
        a2[r][2] = (v2f){av2, av2};
    }

    // per-lane epilogue weights (lane sub<5 owns output dim sub)
    float wv0 = 0.f, wv1 = 0.f, wv2 = 0.f, bvl = 0.f;
    if (sub < DK) {
        wv0 = Wv[sub*3+0]; wv1 = Wv[sub*3+1]; wv2 = Wv[sub*3+2]; bvl = bv[sub];
    }

    float l[4] = {0.f, 0.f, 0.f, 0.f};
    v2f acc2[4][4];              // {p*x0, p*x1, p*x2, p} over past keys
#pragma unroll
    for (int r = 0; r < 4; ++r)
#pragma unroll
        for (int d = 0; d < 4; ++d) acc2[r][d] = (v2f){0.f, 0.f};

    const float* XtB = Xt + (size_t)b * 3 * SS;

    for (int t = 0; t < SS; t += TK) {
        __syncthreads();
        // stage 3 planes x TK: 768 float4 slots, lane-contiguous dest
#pragma unroll
        for (int it = 0; it < 3; ++it) {
            int idx = it * NT + tid;
            int d = idx >> 8, c4 = idx & 255;
            GLOAD16(&XtB[(size_t)d * SS + t + c4 * 4], &kls[d][c4 * 4]);
        }
        __syncthreads();

#pragma unroll
        for (int j = 0; j < TK / 256; ++j) {
            const int cstart = t + j * 256;     // wave-uniform chunk bounds
            const int cend   = cstart + 255;
            const bool anyAcc = (cstart <= hi0 + 1);

#pragma unroll
            for (int h = 0; h < 2; ++h) {       // 2 keys per half (b64 reads)
                const int keyh = j * 256 + sub * 4 + h * 2;
                const int kgh  = t + keyh;

                v2f k0 = *(const v2f*)&kls[0][keyh];
                v2f k1 = *(const v2f*)&kls[1][keyh];
                v2f k2 = *(const v2f*)&kls[2][keyh];

                if (anyAcc) {
#pragma unroll
                    for (int r = 0; r < 4; ++r) {
                        const int row = rows[r];
                        v2f sc = pk_fma(a2[r][0], k0,
                                 pk_fma(a2[r][1], k1, a2[r][2] * k2));
                        v2f p;
                        p.x = fast_exp2(sc.x); p.y = fast_exp2(sc.y);
                        l[r] += p.x + p.y;
                        if (cend <= row) {          // full accumulate
                            acc2[r][0] = pk_fma(p, k0, acc2[r][0]);
                            acc2[r][1] = pk_fma(p, k1, acc2[r][1]);
                            acc2[r][2] = pk_fma(p, k2, acc2[r][2]);
                            acc2[r][3] += p;
                        } else if (cstart <= row) { // boundary: masked
                            v2f pm;
                            pm.x = (kgh + 0 <= row) ? p.x : 0.f;
                            pm.y = (kgh + 1 <= row) ? p.y : 0.f;
                            acc2[r][0] = pk_fma(pm, k0, acc2[r][0]);
                            acc2[r][1] = pk_fma(pm, k1, acc2[r][1]);
                            acc2[r][2] = pk_fma(pm, k2, acc2[r][2]);
                            acc2[r][3] += pm;
                        }
                        // else: future-only for this row -> denominator only
                    }
                } else {
                    // denominator-only chunk for all 4 rows
#pragma unroll
                    for (int r = 0; r < 4; ++r) {
                        v2f sc = pk_fma(a2[r][0], k0,
                                 pk_fma(a2[r][1], k1, a2[r][2] * k2));
                        v2f p;
                        p.x = fast_exp2(sc.x); p.y = fast_exp2(sc.y);
                        l[r] += p.x + p.y;
                    }
                }
            }
        }
    }

    // fold packed halves, butterfly-reduce 5 values across 64 lanes, project
#pragma unroll
    for (int r = 0; r < 4; ++r) {
        float lr = l[r];
        float A0 = acc2[r][0].x + acc2[r][0].y;
        float A1 = acc2[r][1].x + acc2[r][1].y;
        float A2 = acc2[r][2].x + acc2[r][2].y;
        float PS = acc2[r][3].x + acc2[r][3].y;
#pragma unroll
        for (int off = 32; off >= 1; off >>= 1) {
            lr += __shfl_xor(lr, off);
            A0 += __shfl_xor(A0, off);
            A1 += __shfl_xor(A1, off);
            A2 += __shfl_xor(A2, off);
            PS += __shfl_xor(PS, off);
        }
        if (sub < DK) {
            float num = fmaf(wv0, A0, fmaf(wv1, A1, fmaf(wv2, A2, bvl * PS)));
            out[((size_t)b * SS + rows[r]) * DK + sub] = num / lr;
        }
    }
}

extern "C" void kernel_launch(void* const* d_in, const int* in_sizes, int n_in,
                              void* d_out, int out_size, void* d_ws, size_t ws_size,
                              hipStream_t stream) {
    const float* x  = (const float*)d_in[0];
    const float* Wq = (const float*)d_in[1];
    const float* bq = (const float*)d_in[2];
    const float* Wk = (const float*)d_in[3];
    const float* Wv = (const float*)d_in[5];
    const float* bv = (const float*)d_in[6];
    float* outp = (float*)d_out;

    float* Xt = (float*)d_ws;                       // [B][3][S] f32 (196 KB)

    proj_x<<<(BB * SS + NT - 1) / NT, NT, 0, stream>>>(x, Xt);
    attn<<<BB * (SS / 16), NT, 0, stream>>>(x, Wq, bq, Wk, Wv, bv, Xt, outp);
}